// Round 15
// baseline (71.392 us; speedup 1.0000x reference)
//
#include <hip/hip_runtime.h>
#include <hip/hip_fp16.h>
#include <cmath>

#define IN_DIM 64
#define NBLK   128     // blocks for bin-count / bin-place (must be 128: 2 waves scan)
#define BSH    6       // 64 nodes per bucket
#define CAP    3072    // max edges per bucket held in LDS

// fast tanh: 1 - 2/(e^{2x}+1); saturates correctly (+inf->1, -inf->-1)
__device__ __forceinline__ float fast_tanh(float x) {
    return 1.0f - __fdividef(2.0f, __expf(2.0f * x) + 1.0f);
}

__device__ __forceinline__ float2 half2_to_float2(unsigned int u) {
    __half2 h = *reinterpret_cast<__half2*>(&u);
    return __half22float2(h);
}

// ---- K1 fused: node scores (4 nodes/wave, float4) + h->fp16 + bucket count -
__global__ void scores_and_count_kernel(const float* __restrict__ h,
                                        const float* __restrict__ d,
                                        const float* __restrict__ gate_w,
                                        const float* __restrict__ gate_b,
                                        float2* __restrict__ pairD,
                                        float2* __restrict__ pairS,
                                        unsigned short* __restrict__ hh,  // fp16 h
                                        const int* __restrict__ dst,
                                        int* __restrict__ counts,   // [NBLK][NB]
                                        int n_nodes, int n_edges, int NB,
                                        int scoreBlocks) {
    extern __shared__ int cnt[];                  // NB ints (count role only)
    if ((int)blockIdx.x < scoreBlocks) {
        int gid  = blockIdx.x * blockDim.x + threadIdx.x;
        int node = gid >> 4;                      // 16 lanes per node
        int li   = threadIdx.x & 15;              // feature quad index
        if (node >= n_nodes) return;

        const float4 hv = *reinterpret_cast<const float4*>(&h[node * IN_DIM + li * 4]);
        const float4 wd = *reinterpret_cast<const float4*>(&gate_w[li * 4]);
        const float4 ws = *reinterpret_cast<const float4*>(&gate_w[IN_DIM + li * 4]);

        // fp16 copy of h (8B per lane, coalesced)
        ushort4 hq;
        hq.x = __half_as_ushort(__float2half_rn(hv.x));
        hq.y = __half_as_ushort(__float2half_rn(hv.y));
        hq.z = __half_as_ushort(__float2half_rn(hv.z));
        hq.w = __half_as_ushort(__float2half_rn(hv.w));
        *reinterpret_cast<ushort4*>(&hh[node * IN_DIM + li * 4]) = hq;

        float pd = hv.x * wd.x + hv.y * wd.y + hv.z * wd.z + hv.w * wd.w;
        float ps = hv.x * ws.x + hv.y * ws.y + hv.z * ws.z + hv.w * ws.w;
        #pragma unroll
        for (int off = 8; off > 0; off >>= 1) {   // reduce within 16-lane group
            pd += __shfl_xor(pd, off, 64);
            ps += __shfl_xor(ps, off, 64);
        }
        if (li == 0) {
            float dv = d[node];
            pairD[node] = make_float2(pd + gate_b[0], dv);
            pairS[node] = make_float2(ps, dv);
        }
    } else {
        int bk  = blockIdx.x - scoreBlocks;       // 0..NBLK-1
        int tid = threadIdx.x;
        for (int b = tid; b < NB; b += blockDim.x) cnt[b] = 0;
        __syncthreads();
        int slice = (n_edges + NBLK - 1) / NBLK;
        int e0 = bk * slice;
        int e1 = min(e0 + slice, n_edges);
        for (int e = e0 + tid; e < e1; e += blockDim.x)
            atomicAdd(&cnt[dst[e] >> BSH], 1);
        __syncthreads();
        for (int b = tid; b < NB; b += blockDim.x)
            counts[bk * NB + b] = cnt[b];         // coalesced
    }
}

// ---- K2: per-bucket exclusive scan over the NBLK block counts --------------
__global__ void bucket_block_scan_kernel(const int* __restrict__ counts, // [NBLK][NB]
                                         int* __restrict__ within,      // [NB][NBLK]
                                         int* __restrict__ btot,        // [NB]
                                         int NB) {
    __shared__ int w0sum;
    int b   = blockIdx.x;
    int tid = threadIdx.x;                        // NBLK = 128 threads, 2 waves
    int v = counts[tid * NB + b];                 // strided read, L2-hot
    int incl = v;
    #pragma unroll
    for (int dd = 1; dd < 64; dd <<= 1) {
        int t = __shfl_up(incl, dd, 64);
        if ((tid & 63) >= dd) incl += t;
    }
    if (tid == 63) w0sum = incl;
    __syncthreads();
    if (tid >= 64) incl += w0sum;
    within[b * NBLK + tid] = incl - v;            // exclusive, coalesced write
    if (tid == NBLK - 1) btot[b] = incl;
}

// ---- K3: redundant btot scan (3KB, L2-hot) + place into contiguous runs ----
__global__ void bin_place_kernel(const int* __restrict__ src,
                                 const int* __restrict__ dst,
                                 const int* __restrict__ btot,      // [NB]
                                 const int* __restrict__ within,    // [NB][NBLK]
                                 int* __restrict__ bucketBase,      // [NB+1] out (bk 0)
                                 int* __restrict__ entries,
                                 int n_edges, int NB) {
    extern __shared__ int smem[];
    int* base = smem;          // NB: bucketBase[b] + within[b][bk]
    int* cur  = smem + NB;     // NB: btot during scan, then cursor
    __shared__ int wq[4], wp[4];

    int bk  = blockIdx.x;
    int tid = threadIdx.x;                        // 256
    int lane = tid & 63, w = tid >> 6;

    // each thread handles a contiguous chunk of buckets
    int q  = (NB + 255) >> 8;
    int b0 = min(tid * q, NB);
    int b1 = min(b0 + q, NB);

    int csum = 0;
    for (int b = b0; b < b1; ++b) {
        int v = btot[b];
        cur[b] = v;
        csum += v;
    }
    // block-wide exclusive scan of per-thread chunk sums
    int s = csum;
    #pragma unroll
    for (int dd = 1; dd < 64; dd <<= 1) {
        int t = __shfl_up(s, dd, 64);
        if (lane >= dd) s += t;
    }
    if (lane == 63) wq[w] = s;
    __syncthreads();
    if (tid == 0) {
        int run = 0;
        for (int j = 0; j < 4; ++j) { wp[j] = run; run += wq[j]; }
    }
    __syncthreads();
    int run = s - csum + wp[w];                   // exclusive prefix of chunk
    for (int b = b0; b < b1; ++b) {
        int bb = run;                             // bucketBase[b]
        run += cur[b];
        base[b] = bb + within[b * NBLK + bk];     // this block's write base
        if (bk == 0) bucketBase[b] = bb;
    }
    if (bk == 0 && tid == 0) bucketBase[NB] = n_edges;
    __syncthreads();
    for (int b = tid; b < NB; b += 256) cur[b] = 0;    // cursor = 0
    __syncthreads();

    // placement
    int slice = (n_edges + NBLK - 1) / NBLK;
    int e0 = bk * slice;
    int e1 = min(e0 + slice, n_edges);
    for (int e = e0 + tid; e < e1; e += blockDim.x) {
        int t = dst[e];
        int b = t >> BSH;
        int sl = atomicAdd(&cur[b], 1);
        entries[base[b] + sl] = ((t & 63) << 17) | src[e];   // block-local lines
    }
}

// ---- K4 fused: single-global-pass LDS sort + gather + z write --------------
// One block per 64-node bucket; 16 waves -> 4 nodes per wave in the gather.
// Pass1: entries read ONCE -> raw[] + craw[] (c computed here) + histogram.
// Pass2: pure-LDS scatter into epk. Then gather.
__global__ __launch_bounds__(1024)
void sort_gather_kernel(const unsigned short* __restrict__ hh,
                        const int* __restrict__ entries,
                        const int* __restrict__ bucketBase,
                        const float2* __restrict__ pairD,
                        const float2* __restrict__ pairS,
                        float* __restrict__ z,
                        int n_nodes, int NB) {
    __shared__ int   cnt[64];        // histogram, then cursor
    __shared__ int   nodeBeg[65];    // within-bucket CSR starts
    __shared__ float sDl[64];
    __shared__ float dDl[64];
    __shared__ int   raw[CAP];       // staged entries (global read once)
    __shared__ float craw[CAP];      // per-edge coefficient
    __shared__ int2  epk[CAP];       // sorted (src, c)

    int b   = blockIdx.x;
    int tid = threadIdx.x;           // 1024 = 16 waves
    int beg = bucketBase[b];
    int end = bucketBase[b + 1];
    int m   = end - beg;

    if (tid < 64) {
        cnt[tid] = 0;
        int node = (b << BSH) + tid;
        float2 pd = (node < n_nodes) ? pairD[node] : make_float2(0.f, 0.f);
        sDl[tid] = pd.x;
        dDl[tid] = pd.y;
    }
    __syncthreads();

    int w    = tid >> 6;             // 0..15
    int lane = tid & 63;
    int slot = lane >> 3;            // 0..7 edge slot
    int oct  = lane & 7;             // features [oct*8, oct*8+8)
    const int2 zero2 = make_int2(0, 0);

    if (m <= CAP) {
        // pass1: stage + histogram + coefficient (one global entries read)
        for (int j = beg + tid; j < end; j += 1024) {
            int e  = entries[j];
            int dl = e >> 17;
            int s  = e & 0x1FFFF;
            raw[j - beg] = e;
            float2 ps = pairS[s];                 // random 8B, TLP-hidden
            craw[j - beg] = fast_tanh(sDl[dl] + ps.x) * ps.y * dDl[dl];
            atomicAdd(&cnt[dl], 1);
        }
        __syncthreads();
        // scan 64 bins (wave 0) -> nodeBeg, reset cnt to cursor
        if (tid < 64) {
            int v = cnt[tid];
            int incl = v;
            #pragma unroll
            for (int dd = 1; dd < 64; dd <<= 1) {
                int t = __shfl_up(incl, dd, 64);
                if (tid >= dd) incl += t;
            }
            int excl = incl - v;
            nodeBeg[tid] = excl;
            cnt[tid] = excl;
            if (tid == 0) nodeBeg[64] = m;
        }
        __syncthreads();
        // pass2: pure-LDS scatter into epk
        for (int j = tid; j < m; j += 1024) {
            int e  = raw[j];
            int dl = e >> 17;
            int pos = atomicAdd(&cnt[dl], 1);
            epk[pos] = make_int2(e & 0x1FFFF, __float_as_int(craw[j]));
        }
        __syncthreads();

        // gather: each wave handles 4 nodes (r = w, w+16, w+32, w+48)
        for (int r = w; r < 64; r += 16) {
            int node = (b << BSH) + r;
            if (node >= n_nodes) break;
            int nb = nodeBeg[r];
            int ne = nodeBeg[r + 1];

            float a0[8], a1[8];
            #pragma unroll
            for (int k = 0; k < 8; ++k) { a0[k] = 0.f; a1[k] = 0.f; }

            for (int base2 = nb; base2 < ne; base2 += 16) {
                int j0 = base2 + slot;
                int j1 = base2 + 8 + slot;
                int2 e0 = (j0 < ne) ? epk[j0] : zero2;   // c = 0 when invalid
                int2 e1 = (j1 < ne) ? epk[j1] : zero2;
                const uint4 q0 = *reinterpret_cast<const uint4*>(
                    &hh[(size_t)e0.x * IN_DIM + oct * 8]);
                const uint4 q1 = *reinterpret_cast<const uint4*>(
                    &hh[(size_t)e1.x * IN_DIM + oct * 8]);
                float c0 = __int_as_float(e0.y);
                float c1 = __int_as_float(e1.y);
                float2 f;
                f = half2_to_float2(q0.x); a0[0] = fmaf(f.x, c0, a0[0]); a0[1] = fmaf(f.y, c0, a0[1]);
                f = half2_to_float2(q0.y); a0[2] = fmaf(f.x, c0, a0[2]); a0[3] = fmaf(f.y, c0, a0[3]);
                f = half2_to_float2(q0.z); a0[4] = fmaf(f.x, c0, a0[4]); a0[5] = fmaf(f.y, c0, a0[5]);
                f = half2_to_float2(q0.w); a0[6] = fmaf(f.x, c0, a0[6]); a0[7] = fmaf(f.y, c0, a0[7]);
                f = half2_to_float2(q1.x); a1[0] = fmaf(f.x, c1, a1[0]); a1[1] = fmaf(f.y, c1, a1[1]);
                f = half2_to_float2(q1.y); a1[2] = fmaf(f.x, c1, a1[2]); a1[3] = fmaf(f.y, c1, a1[3]);
                f = half2_to_float2(q1.z); a1[4] = fmaf(f.x, c1, a1[4]); a1[5] = fmaf(f.y, c1, a1[5]);
                f = half2_to_float2(q1.w); a1[6] = fmaf(f.x, c1, a1[6]); a1[7] = fmaf(f.y, c1, a1[7]);
            }

            float a[8];
            #pragma unroll
            for (int k = 0; k < 8; ++k) a[k] = a0[k] + a1[k];
            #pragma unroll
            for (int mm = 8; mm < 64; mm <<= 1) {
                #pragma unroll
                for (int k = 0; k < 8; ++k) a[k] += __shfl_xor(a[k], mm, 64);
            }
            if (slot == 0) {
                float4 lo = make_float4(a[0], a[1], a[2], a[3]);
                float4 hi = make_float4(a[4], a[5], a[6], a[7]);
                *reinterpret_cast<float4*>(&z[(size_t)node * IN_DIM + oct * 8])     = lo;
                *reinterpret_cast<float4*>(&z[(size_t)node * IN_DIM + oct * 8 + 4]) = hi;
            }
        }
    } else {
        // pathological bucket (> CAP edges): quadratic per-node scan.
        for (int r = w; r < 64; r += 16) {
            int node = (b << BSH) + r;
            if (node >= n_nodes) break;
            float a[8];
            #pragma unroll
            for (int k = 0; k < 8; ++k) a[k] = 0.f;
            for (int j = beg + slot; j < end; j += 8) {
                int e = entries[j];
                if ((e >> 17) != r) continue;
                int s = e & 0x1FFFF;
                float2 ps = pairS[s];
                float c = fast_tanh(sDl[r] + ps.x) * ps.y * dDl[r];
                const uint4 q = *reinterpret_cast<const uint4*>(
                    &hh[(size_t)s * IN_DIM + oct * 8]);
                float2 f;
                f = half2_to_float2(q.x); a[0] = fmaf(f.x, c, a[0]); a[1] = fmaf(f.y, c, a[1]);
                f = half2_to_float2(q.y); a[2] = fmaf(f.x, c, a[2]); a[3] = fmaf(f.y, c, a[3]);
                f = half2_to_float2(q.z); a[4] = fmaf(f.x, c, a[4]); a[5] = fmaf(f.y, c, a[5]);
                f = half2_to_float2(q.w); a[6] = fmaf(f.x, c, a[6]); a[7] = fmaf(f.y, c, a[7]);
            }
            #pragma unroll
            for (int mm = 8; mm < 64; mm <<= 1) {
                #pragma unroll
                for (int k = 0; k < 8; ++k) a[k] += __shfl_xor(a[k], mm, 64);
            }
            if (slot == 0) {
                float4 lo = make_float4(a[0], a[1], a[2], a[3]);
                float4 hi = make_float4(a[4], a[5], a[6], a[7]);
                *reinterpret_cast<float4*>(&z[(size_t)node * IN_DIM + oct * 8])     = lo;
                *reinterpret_cast<float4*>(&z[(size_t)node * IN_DIM + oct * 8 + 4]) = hi;
            }
        }
    }
}

// ---- fallback (atomic push) ------------------------------------------------
__global__ void node_scores_kernel(const float* __restrict__ h,
                                   const float* __restrict__ d,
                                   const float* __restrict__ gate_w,
                                   const float* __restrict__ gate_b,
                                   float2* __restrict__ pairD,
                                   float2* __restrict__ pairS,
                                   int n_nodes) {
    int gid  = blockIdx.x * blockDim.x + threadIdx.x;
    int node = gid >> 6;
    int lane = threadIdx.x & 63;
    if (node >= n_nodes) return;
    float hv = h[node * IN_DIM + lane];
    float pd = hv * gate_w[lane];
    float ps = hv * gate_w[IN_DIM + lane];
    #pragma unroll
    for (int off = 32; off > 0; off >>= 1) {
        pd += __shfl_xor(pd, off, 64);
        ps += __shfl_xor(ps, off, 64);
    }
    if (lane == 0) {
        float dv = d[node];
        pairD[node] = make_float2(pd + gate_b[0], dv);
        pairS[node] = make_float2(ps, dv);
    }
}

__global__ void edge_scatter_atomic_kernel(const float* __restrict__ h,
                                           const int* __restrict__ src,
                                           const int* __restrict__ dst,
                                           const float2* __restrict__ pairD,
                                           const float2* __restrict__ pairS,
                                           float* __restrict__ z,
                                           int n_edges) {
    int gid  = blockIdx.x * blockDim.x + threadIdx.x;
    int e    = gid >> 6;
    int lane = threadIdx.x & 63;
    if (e >= n_edges) return;
    int s = src[e];
    int t = dst[e];
    float2 pt = pairD[t];
    float2 ps = pairS[s];
    float c = tanhf(pt.x + ps.x) * pt.y * ps.y;
    atomicAdd(&z[t * IN_DIM + lane], h[s * IN_DIM + lane] * c);
}

extern "C" void kernel_launch(void* const* d_in, const int* in_sizes, int n_in,
                              void* d_out, int out_size, void* d_ws, size_t ws_size,
                              hipStream_t stream) {
    const float* h      = (const float*)d_in[0];
    const float* d      = (const float*)d_in[1];
    const int*   src    = (const int*)d_in[2];
    const int*   dst    = (const int*)d_in[3];
    const float* gate_w = (const float*)d_in[4];
    const float* gate_b = (const float*)d_in[5];

    const int n_nodes = in_sizes[1];
    const int n_edges = in_sizes[2];
    float* z = (float*)d_out;

    const int NB = (n_nodes + 63) >> BSH;   // 64-node buckets (782)

    // ws layout: pairD, pairS, hh (fp16 h), entries, counts, within, btot,
    //            bucketBase
    size_t need = (size_t)n_nodes * 2 * sizeof(float2)
                + (size_t)n_nodes * IN_DIM * sizeof(unsigned short)
                + (size_t)n_edges * sizeof(int)
                + (size_t)(2 * NB * NBLK + 2 * NB + 1) * sizeof(int);

    if (ws_size < need || NB > 1024 || n_nodes > (1 << 17)) {
        float2* pairD = (float2*)d_ws;
        float2* pairS = pairD + n_nodes;
        hipMemsetAsync(z, 0, (size_t)out_size * sizeof(float), stream);
        {
            int total = n_nodes * 64, threads = 256;
            node_scores_kernel<<<(total + threads - 1) / threads, threads, 0, stream>>>(
                h, d, gate_w, gate_b, pairD, pairS, n_nodes);
        }
        {
            long long total = (long long)n_edges * 64;
            int threads = 256;
            edge_scatter_atomic_kernel<<<(int)((total + threads - 1) / threads), threads, 0, stream>>>(
                h, src, dst, pairD, pairS, z, n_edges);
        }
        return;
    }

    float2*         pairD      = (float2*)d_ws;
    float2*         pairS      = pairD + n_nodes;
    unsigned short* hh         = (unsigned short*)(pairS + n_nodes);
    int*            entries    = (int*)(hh + (size_t)n_nodes * IN_DIM);
    int*            counts     = entries + n_edges;         // [NBLK][NB]
    int*            within     = counts + NBLK * NB;        // [NB][NBLK]
    int*            btot       = within + NB * NBLK;        // NB
    int*            bucketBase = btot + NB;                 // NB+1

    const int scoreBlocks = (n_nodes * 16 + 255) / 256;     // 4 nodes per wave

    // K1: node scores (float4) + h->fp16 + per-block bucket histogram
    scores_and_count_kernel<<<scoreBlocks + NBLK, 256, NB * sizeof(int), stream>>>(
        h, d, gate_w, gate_b, pairD, pairS, hh, dst, counts,
        n_nodes, n_edges, NB, scoreBlocks);

    // K2: per-bucket scan across blocks -> within, btot
    bucket_block_scan_kernel<<<NB, NBLK, 0, stream>>>(counts, within, btot, NB);

    // K3: redundant btot scan + place (block 0 publishes bucketBase)
    bin_place_kernel<<<NBLK, 256, 2 * NB * sizeof(int), stream>>>(
        src, dst, btot, within, bucketBase, entries, n_edges, NB);

    // K4: fused single-pass LDS sort + gather + z write (1024 threads/bucket)
    sort_gather_kernel<<<NB, 1024, 0, stream>>>(
        hh, entries, bucketBase, pairD, pairS, z, n_nodes, NB);
}

// Round 16
// 61.794 us; speedup vs baseline: 1.1553x; 1.1553x over previous
//
#include <hip/hip_runtime.h>
#include <hip/hip_fp16.h>
#include <cmath>

#define IN_DIM 64
#define NBLK   128     // blocks for bin-count / bin-place
#define BSH    6       // 64 nodes per bucket
#define CAP    3072    // max edges per bucket held in LDS
#define SGT    512     // sort_gather threads (3 blocks/CU by LDS -> 768 concurrent)

// slice of edges per count/place block — MUST be identical in K1 and K3,
// and a multiple of 4 so int4 loads are 16B-aligned.
__host__ __device__ __forceinline__ int edge_slice(int n_edges) {
    return (((n_edges + NBLK - 1) / NBLK) + 3) & ~3;
}

// fast tanh: 1 - 2/(e^{2x}+1); saturates correctly (+inf->1, -inf->-1)
__device__ __forceinline__ float fast_tanh(float x) {
    return 1.0f - __fdividef(2.0f, __expf(2.0f * x) + 1.0f);
}

__device__ __forceinline__ float2 half2_to_float2(unsigned int u) {
    __half2 h = *reinterpret_cast<__half2*>(&u);
    return __half22float2(h);
}

// ---- K1 fused: node scores (4 nodes/wave, float4) + h->fp16 + bucket count -
__global__ void scores_and_count_kernel(const float* __restrict__ h,
                                        const float* __restrict__ d,
                                        const float* __restrict__ gate_w,
                                        const float* __restrict__ gate_b,
                                        float2* __restrict__ pairD,
                                        float2* __restrict__ pairS,
                                        unsigned short* __restrict__ hh,  // fp16 h
                                        const int* __restrict__ dst,
                                        int* __restrict__ counts,   // [NBLK][NB]
                                        int n_nodes, int n_edges, int NB,
                                        int scoreBlocks) {
    extern __shared__ int cnt[];                  // NB ints (count role only)
    if ((int)blockIdx.x < scoreBlocks) {
        int gid  = blockIdx.x * blockDim.x + threadIdx.x;
        int node = gid >> 4;                      // 16 lanes per node
        int li   = threadIdx.x & 15;              // feature quad index
        if (node >= n_nodes) return;

        const float4 hv = *reinterpret_cast<const float4*>(&h[node * IN_DIM + li * 4]);
        const float4 wd = *reinterpret_cast<const float4*>(&gate_w[li * 4]);
        const float4 ws = *reinterpret_cast<const float4*>(&gate_w[IN_DIM + li * 4]);

        ushort4 hq;
        hq.x = __half_as_ushort(__float2half_rn(hv.x));
        hq.y = __half_as_ushort(__float2half_rn(hv.y));
        hq.z = __half_as_ushort(__float2half_rn(hv.z));
        hq.w = __half_as_ushort(__float2half_rn(hv.w));
        *reinterpret_cast<ushort4*>(&hh[node * IN_DIM + li * 4]) = hq;

        float pd = hv.x * wd.x + hv.y * wd.y + hv.z * wd.z + hv.w * wd.w;
        float ps = hv.x * ws.x + hv.y * ws.y + hv.z * ws.z + hv.w * ws.w;
        #pragma unroll
        for (int off = 8; off > 0; off >>= 1) {   // reduce within 16-lane group
            pd += __shfl_xor(pd, off, 64);
            ps += __shfl_xor(ps, off, 64);
        }
        if (li == 0) {
            float dv = d[node];
            pairD[node] = make_float2(pd + gate_b[0], dv);
            pairS[node] = make_float2(ps, dv);
        }
    } else {
        int bk  = blockIdx.x - scoreBlocks;       // 0..NBLK-1
        int tid = threadIdx.x;
        for (int b = tid; b < NB; b += blockDim.x) cnt[b] = 0;
        __syncthreads();
        int slice = edge_slice(n_edges);
        int e0 = bk * slice;
        int e1 = min(e0 + slice, n_edges);
        // int4 reads: e0 is 16B-aligned (slice % 4 == 0)
        for (int e = e0 + tid * 4; e < e1; e += blockDim.x * 4) {
            if (e + 3 < e1) {
                int4 t4 = *reinterpret_cast<const int4*>(&dst[e]);
                atomicAdd(&cnt[t4.x >> BSH], 1);
                atomicAdd(&cnt[t4.y >> BSH], 1);
                atomicAdd(&cnt[t4.z >> BSH], 1);
                atomicAdd(&cnt[t4.w >> BSH], 1);
            } else {
                for (int k = e; k < e1; ++k) atomicAdd(&cnt[dst[k] >> BSH], 1);
            }
        }
        __syncthreads();
        for (int b = tid; b < NB; b += blockDim.x)
            counts[bk * NB + b] = cnt[b];         // coalesced
    }
}

// ---- K2: per-bucket exclusive scan over the NBLK block counts --------------
__global__ void bucket_block_scan_kernel(const int* __restrict__ counts, // [NBLK][NB]
                                         int* __restrict__ within,      // [NB][NBLK]
                                         int* __restrict__ btot,        // [NB]
                                         int NB) {
    __shared__ int w0sum;
    int b   = blockIdx.x;
    int tid = threadIdx.x;                        // NBLK = 128 threads, 2 waves
    int v = counts[tid * NB + b];                 // strided read, L2-hot
    int incl = v;
    #pragma unroll
    for (int dd = 1; dd < 64; dd <<= 1) {
        int t = __shfl_up(incl, dd, 64);
        if ((tid & 63) >= dd) incl += t;
    }
    if (tid == 63) w0sum = incl;
    __syncthreads();
    if (tid >= 64) incl += w0sum;
    within[b * NBLK + tid] = incl - v;            // exclusive, coalesced write
    if (tid == NBLK - 1) btot[b] = incl;
}

// ---- K3: redundant btot scan (3KB, L2-hot) + place into contiguous runs ----
__global__ void bin_place_kernel(const int* __restrict__ src,
                                 const int* __restrict__ dst,
                                 const int* __restrict__ btot,      // [NB]
                                 const int* __restrict__ within,    // [NB][NBLK]
                                 int* __restrict__ bucketBase,      // [NB+1] out (bk 0)
                                 int* __restrict__ entries,
                                 int n_edges, int NB) {
    extern __shared__ int smem[];
    int* base = smem;          // NB: bucketBase[b] + within[b][bk]
    int* cur  = smem + NB;     // NB: btot during scan, then cursor
    __shared__ int wq[4], wp[4];

    int bk  = blockIdx.x;
    int tid = threadIdx.x;                        // 256
    int lane = tid & 63, w = tid >> 6;

    int q  = (NB + 255) >> 8;
    int b0 = min(tid * q, NB);
    int b1 = min(b0 + q, NB);

    int csum = 0;
    for (int b = b0; b < b1; ++b) {
        int v = btot[b];
        cur[b] = v;
        csum += v;
    }
    int s = csum;
    #pragma unroll
    for (int dd = 1; dd < 64; dd <<= 1) {
        int t = __shfl_up(s, dd, 64);
        if (lane >= dd) s += t;
    }
    if (lane == 63) wq[w] = s;
    __syncthreads();
    if (tid == 0) {
        int run = 0;
        for (int j = 0; j < 4; ++j) { wp[j] = run; run += wq[j]; }
    }
    __syncthreads();
    int run = s - csum + wp[w];
    for (int b = b0; b < b1; ++b) {
        int bb = run;                             // bucketBase[b]
        run += cur[b];
        base[b] = bb + within[b * NBLK + bk];
        if (bk == 0) bucketBase[b] = bb;
    }
    if (bk == 0 && tid == 0) bucketBase[NB] = n_edges;
    __syncthreads();
    for (int b = tid; b < NB; b += 256) cur[b] = 0;
    __syncthreads();

    // placement, int4 edge reads (e0 16B-aligned since slice % 4 == 0)
    int slice = edge_slice(n_edges);
    int e0 = bk * slice;
    int e1 = min(e0 + slice, n_edges);
    for (int e = e0 + tid * 4; e < e1; e += blockDim.x * 4) {
        if (e + 3 < e1) {
            int4 t4 = *reinterpret_cast<const int4*>(&dst[e]);
            int4 s4 = *reinterpret_cast<const int4*>(&src[e]);
            int b0i = t4.x >> BSH, b1i = t4.y >> BSH,
                b2i = t4.z >> BSH, b3i = t4.w >> BSH;
            int p0 = atomicAdd(&cur[b0i], 1);
            int p1 = atomicAdd(&cur[b1i], 1);
            int p2 = atomicAdd(&cur[b2i], 1);
            int p3 = atomicAdd(&cur[b3i], 1);
            entries[base[b0i] + p0] = ((t4.x & 63) << 17) | s4.x;
            entries[base[b1i] + p1] = ((t4.y & 63) << 17) | s4.y;
            entries[base[b2i] + p2] = ((t4.z & 63) << 17) | s4.z;
            entries[base[b3i] + p3] = ((t4.w & 63) << 17) | s4.w;
        } else {
            for (int k = e; k < e1; ++k) {
                int t = dst[k];
                int b = t >> BSH;
                int sl = atomicAdd(&cur[b], 1);
                entries[base[b] + sl] = ((t & 63) << 17) | src[k];
            }
        }
    }
}

// ---- K4 fused: single-pass LDS sort + gather + z write, 512 threads/block --
// 512 threads -> ~50KB LDS -> 3 blocks/CU -> 768 concurrent blocks (no tail).
__global__ __launch_bounds__(SGT)
void sort_gather_kernel(const unsigned short* __restrict__ hh,
                        const int* __restrict__ entries,
                        const int* __restrict__ bucketBase,
                        const float2* __restrict__ pairD,
                        const float2* __restrict__ pairS,
                        float* __restrict__ z,
                        int n_nodes, int NB) {
    __shared__ int   cnt[64];        // histogram, then cursor
    __shared__ int   nodeBeg[65];    // within-bucket CSR starts
    __shared__ float sDl[64];
    __shared__ float dDl[64];
    __shared__ int   raw[CAP];       // staged entries (global read once)
    __shared__ float craw[CAP];      // per-edge coefficient
    __shared__ int2  epk[CAP];       // sorted (src, c)

    int b   = blockIdx.x;
    int tid = threadIdx.x;           // 512 = 8 waves
    int beg = bucketBase[b];
    int end = bucketBase[b + 1];
    int m   = end - beg;

    if (tid < 64) {
        cnt[tid] = 0;
        int node = (b << BSH) + tid;
        float2 pd = (node < n_nodes) ? pairD[node] : make_float2(0.f, 0.f);
        sDl[tid] = pd.x;
        dDl[tid] = pd.y;
    }
    __syncthreads();

    int w    = tid >> 6;             // 0..7
    int lane = tid & 63;
    int slot = lane >> 3;            // 0..7 edge slot
    int oct  = lane & 7;             // features [oct*8, oct*8+8)
    const int2 zero2 = make_int2(0, 0);

    if (m <= CAP) {
        // pass1: stage + histogram + coefficient (one global entries read)
        for (int j = beg + tid; j < end; j += SGT) {
            int e  = entries[j];
            int dl = e >> 17;
            int s  = e & 0x1FFFF;
            raw[j - beg] = e;
            float2 ps = pairS[s];                 // random 8B, TLP-hidden
            craw[j - beg] = fast_tanh(sDl[dl] + ps.x) * ps.y * dDl[dl];
            atomicAdd(&cnt[dl], 1);
        }
        __syncthreads();
        // scan 64 bins (wave 0) -> nodeBeg, reset cnt to cursor
        if (tid < 64) {
            int v = cnt[tid];
            int incl = v;
            #pragma unroll
            for (int dd = 1; dd < 64; dd <<= 1) {
                int t = __shfl_up(incl, dd, 64);
                if (tid >= dd) incl += t;
            }
            int excl = incl - v;
            nodeBeg[tid] = excl;
            cnt[tid] = excl;
            if (tid == 0) nodeBeg[64] = m;
        }
        __syncthreads();
        // pass2: pure-LDS scatter into epk
        for (int j = tid; j < m; j += SGT) {
            int e  = raw[j];
            int dl = e >> 17;
            int pos = atomicAdd(&cnt[dl], 1);
            epk[pos] = make_int2(e & 0x1FFFF, __float_as_int(craw[j]));
        }
        __syncthreads();

        // gather: each wave handles 8 nodes (r = w, w+8, ..., w+56)
        for (int r = w; r < 64; r += 8) {
            int node = (b << BSH) + r;
            if (node >= n_nodes) break;
            int nb = nodeBeg[r];
            int ne = nodeBeg[r + 1];

            float a0[8], a1[8];
            #pragma unroll
            for (int k = 0; k < 8; ++k) { a0[k] = 0.f; a1[k] = 0.f; }

            for (int base2 = nb; base2 < ne; base2 += 16) {
                int j0 = base2 + slot;
                int j1 = base2 + 8 + slot;
                int2 e0 = (j0 < ne) ? epk[j0] : zero2;   // c = 0 when invalid
                int2 e1 = (j1 < ne) ? epk[j1] : zero2;
                const uint4 q0 = *reinterpret_cast<const uint4*>(
                    &hh[(size_t)e0.x * IN_DIM + oct * 8]);
                const uint4 q1 = *reinterpret_cast<const uint4*>(
                    &hh[(size_t)e1.x * IN_DIM + oct * 8]);
                float c0 = __int_as_float(e0.y);
                float c1 = __int_as_float(e1.y);
                float2 f;
                f = half2_to_float2(q0.x); a0[0] = fmaf(f.x, c0, a0[0]); a0[1] = fmaf(f.y, c0, a0[1]);
                f = half2_to_float2(q0.y); a0[2] = fmaf(f.x, c0, a0[2]); a0[3] = fmaf(f.y, c0, a0[3]);
                f = half2_to_float2(q0.z); a0[4] = fmaf(f.x, c0, a0[4]); a0[5] = fmaf(f.y, c0, a0[5]);
                f = half2_to_float2(q0.w); a0[6] = fmaf(f.x, c0, a0[6]); a0[7] = fmaf(f.y, c0, a0[7]);
                f = half2_to_float2(q1.x); a1[0] = fmaf(f.x, c1, a1[0]); a1[1] = fmaf(f.y, c1, a1[1]);
                f = half2_to_float2(q1.y); a1[2] = fmaf(f.x, c1, a1[2]); a1[3] = fmaf(f.y, c1, a1[3]);
                f = half2_to_float2(q1.z); a1[4] = fmaf(f.x, c1, a1[4]); a1[5] = fmaf(f.y, c1, a1[5]);
                f = half2_to_float2(q1.w); a1[6] = fmaf(f.x, c1, a1[6]); a1[7] = fmaf(f.y, c1, a1[7]);
            }

            float a[8];
            #pragma unroll
            for (int k = 0; k < 8; ++k) a[k] = a0[k] + a1[k];
            #pragma unroll
            for (int mm = 8; mm < 64; mm <<= 1) {
                #pragma unroll
                for (int k = 0; k < 8; ++k) a[k] += __shfl_xor(a[k], mm, 64);
            }
            if (slot == 0) {
                float4 lo = make_float4(a[0], a[1], a[2], a[3]);
                float4 hi = make_float4(a[4], a[5], a[6], a[7]);
                *reinterpret_cast<float4*>(&z[(size_t)node * IN_DIM + oct * 8])     = lo;
                *reinterpret_cast<float4*>(&z[(size_t)node * IN_DIM + oct * 8 + 4]) = hi;
            }
        }
    } else {
        // pathological bucket (> CAP edges): quadratic per-node scan.
        for (int r = w; r < 64; r += 8) {
            int node = (b << BSH) + r;
            if (node >= n_nodes) break;
            float a[8];
            #pragma unroll
            for (int k = 0; k < 8; ++k) a[k] = 0.f;
            for (int j = beg + slot; j < end; j += 8) {
                int e = entries[j];
                if ((e >> 17) != r) continue;
                int s = e & 0x1FFFF;
                float2 ps = pairS[s];
                float c = fast_tanh(sDl[r] + ps.x) * ps.y * dDl[r];
                const uint4 q = *reinterpret_cast<const uint4*>(
                    &hh[(size_t)s * IN_DIM + oct * 8]);
                float2 f;
                f = half2_to_float2(q.x); a[0] = fmaf(f.x, c, a[0]); a[1] = fmaf(f.y, c, a[1]);
                f = half2_to_float2(q.y); a[2] = fmaf(f.x, c, a[2]); a[3] = fmaf(f.y, c, a[3]);
                f = half2_to_float2(q.z); a[4] = fmaf(f.x, c, a[4]); a[5] = fmaf(f.y, c, a[5]);
                f = half2_to_float2(q.w); a[6] = fmaf(f.x, c, a[6]); a[7] = fmaf(f.y, c, a[7]);
            }
            #pragma unroll
            for (int mm = 8; mm < 64; mm <<= 1) {
                #pragma unroll
                for (int k = 0; k < 8; ++k) a[k] += __shfl_xor(a[k], mm, 64);
            }
            if (slot == 0) {
                float4 lo = make_float4(a[0], a[1], a[2], a[3]);
                float4 hi = make_float4(a[4], a[5], a[6], a[7]);
                *reinterpret_cast<float4*>(&z[(size_t)node * IN_DIM + oct * 8])     = lo;
                *reinterpret_cast<float4*>(&z[(size_t)node * IN_DIM + oct * 8 + 4]) = hi;
            }
        }
    }
}

// ---- fallback (atomic push) ------------------------------------------------
__global__ void node_scores_kernel(const float* __restrict__ h,
                                   const float* __restrict__ d,
                                   const float* __restrict__ gate_w,
                                   const float* __restrict__ gate_b,
                                   float2* __restrict__ pairD,
                                   float2* __restrict__ pairS,
                                   int n_nodes) {
    int gid  = blockIdx.x * blockDim.x + threadIdx.x;
    int node = gid >> 6;
    int lane = threadIdx.x & 63;
    if (node >= n_nodes) return;
    float hv = h[node * IN_DIM + lane];
    float pd = hv * gate_w[lane];
    float ps = hv * gate_w[IN_DIM + lane];
    #pragma unroll
    for (int off = 32; off > 0; off >>= 1) {
        pd += __shfl_xor(pd, off, 64);
        ps += __shfl_xor(ps, off, 64);
    }
    if (lane == 0) {
        float dv = d[node];
        pairD[node] = make_float2(pd + gate_b[0], dv);
        pairS[node] = make_float2(ps, dv);
    }
}

__global__ void edge_scatter_atomic_kernel(const float* __restrict__ h,
                                           const int* __restrict__ src,
                                           const int* __restrict__ dst,
                                           const float2* __restrict__ pairD,
                                           const float2* __restrict__ pairS,
                                           float* __restrict__ z,
                                           int n_edges) {
    int gid  = blockIdx.x * blockDim.x + threadIdx.x;
    int e    = gid >> 6;
    int lane = threadIdx.x & 63;
    if (e >= n_edges) return;
    int s = src[e];
    int t = dst[e];
    float2 pt = pairD[t];
    float2 ps = pairS[s];
    float c = tanhf(pt.x + ps.x) * pt.y * ps.y;
    atomicAdd(&z[t * IN_DIM + lane], h[s * IN_DIM + lane] * c);
}

extern "C" void kernel_launch(void* const* d_in, const int* in_sizes, int n_in,
                              void* d_out, int out_size, void* d_ws, size_t ws_size,
                              hipStream_t stream) {
    const float* h      = (const float*)d_in[0];
    const float* d      = (const float*)d_in[1];
    const int*   src    = (const int*)d_in[2];
    const int*   dst    = (const int*)d_in[3];
    const float* gate_w = (const float*)d_in[4];
    const float* gate_b = (const float*)d_in[5];

    const int n_nodes = in_sizes[1];
    const int n_edges = in_sizes[2];
    float* z = (float*)d_out;

    const int NB = (n_nodes + 63) >> BSH;   // 64-node buckets (782)

    // ws layout: pairD, pairS, hh (fp16 h), entries, counts, within, btot,
    //            bucketBase
    size_t need = (size_t)n_nodes * 2 * sizeof(float2)
                + (size_t)n_nodes * IN_DIM * sizeof(unsigned short)
                + (size_t)n_edges * sizeof(int)
                + (size_t)(2 * NB * NBLK + 2 * NB + 1) * sizeof(int);

    if (ws_size < need || NB > 1024 || n_nodes > (1 << 17)) {
        float2* pairD = (float2*)d_ws;
        float2* pairS = pairD + n_nodes;
        hipMemsetAsync(z, 0, (size_t)out_size * sizeof(float), stream);
        {
            int total = n_nodes * 64, threads = 256;
            node_scores_kernel<<<(total + threads - 1) / threads, threads, 0, stream>>>(
                h, d, gate_w, gate_b, pairD, pairS, n_nodes);
        }
        {
            long long total = (long long)n_edges * 64;
            int threads = 256;
            edge_scatter_atomic_kernel<<<(int)((total + threads - 1) / threads), threads, 0, stream>>>(
                h, src, dst, pairD, pairS, z, n_edges);
        }
        return;
    }

    float2*         pairD      = (float2*)d_ws;
    float2*         pairS      = pairD + n_nodes;
    unsigned short* hh         = (unsigned short*)(pairS + n_nodes);
    int*            entries    = (int*)(hh + (size_t)n_nodes * IN_DIM);
    int*            counts     = entries + n_edges;         // [NBLK][NB]
    int*            within     = counts + NBLK * NB;        // [NB][NBLK]
    int*            btot       = within + NB * NBLK;        // NB
    int*            bucketBase = btot + NB;                 // NB+1

    const int scoreBlocks = (n_nodes * 16 + 255) / 256;     // 4 nodes per wave

    // K1: node scores (float4) + h->fp16 + per-block bucket histogram
    scores_and_count_kernel<<<scoreBlocks + NBLK, 256, NB * sizeof(int), stream>>>(
        h, d, gate_w, gate_b, pairD, pairS, hh, dst, counts,
        n_nodes, n_edges, NB, scoreBlocks);

    // K2: per-bucket scan across blocks -> within, btot
    bucket_block_scan_kernel<<<NB, NBLK, 0, stream>>>(counts, within, btot, NB);

    // K3: redundant btot scan + place (block 0 publishes bucketBase)
    bin_place_kernel<<<NBLK, 256, 2 * NB * sizeof(int), stream>>>(
        src, dst, btot, within, bucketBase, entries, n_edges, NB);

    // K4: fused single-pass LDS sort + gather + z write (512 threads/bucket)
    sort_gather_kernel<<<NB, SGT, 0, stream>>>(
        hh, entries, bucketBase, pairD, pairS, z, n_nodes, NB);
}

// Round 17
// 57.260 us; speedup vs baseline: 1.2468x; 1.0792x over previous
//
#include <hip/hip_runtime.h>
#include <hip/hip_fp16.h>
#include <cmath>

#define IN_DIM 64
#define NBLK   256     // blocks for bin-count / bin-place (== K2 scan width)
#define BSH    6       // 64 nodes per bucket
#define CAP    3072    // max edges per bucket held in LDS
#define SGT    512     // sort_gather threads (38KB LDS -> 4 blocks/CU -> 1024 concurrent)

// slice of edges per count/place block — identical in K1 and K3, multiple of 4
__host__ __device__ __forceinline__ int edge_slice(int n_edges) {
    return (((n_edges + NBLK - 1) / NBLK) + 3) & ~3;
}

// fast tanh: 1 - 2/(e^{2x}+1); saturates correctly (+inf->1, -inf->-1)
__device__ __forceinline__ float fast_tanh(float x) {
    return 1.0f - __fdividef(2.0f, __expf(2.0f * x) + 1.0f);
}

__device__ __forceinline__ float2 half2_to_float2(unsigned int u) {
    __half2 h = *reinterpret_cast<__half2*>(&u);
    return __half22float2(h);
}

// ---- K1 fused: node scores (4 nodes/wave, float4) + h->fp16 + bucket count -
__global__ void scores_and_count_kernel(const float* __restrict__ h,
                                        const float* __restrict__ d,
                                        const float* __restrict__ gate_w,
                                        const float* __restrict__ gate_b,
                                        float2* __restrict__ pairD,
                                        float2* __restrict__ pairS,
                                        unsigned short* __restrict__ hh,  // fp16 h
                                        const int* __restrict__ dst,
                                        int* __restrict__ counts,   // [NBLK][NB]
                                        int n_nodes, int n_edges, int NB,
                                        int scoreBlocks) {
    extern __shared__ int cnt[];                  // NB ints (count role only)
    if ((int)blockIdx.x < scoreBlocks) {
        int gid  = blockIdx.x * blockDim.x + threadIdx.x;
        int node = gid >> 4;                      // 16 lanes per node
        int li   = threadIdx.x & 15;              // feature quad index
        if (node >= n_nodes) return;

        const float4 hv = *reinterpret_cast<const float4*>(&h[node * IN_DIM + li * 4]);
        const float4 wd = *reinterpret_cast<const float4*>(&gate_w[li * 4]);
        const float4 ws = *reinterpret_cast<const float4*>(&gate_w[IN_DIM + li * 4]);

        ushort4 hq;
        hq.x = __half_as_ushort(__float2half_rn(hv.x));
        hq.y = __half_as_ushort(__float2half_rn(hv.y));
        hq.z = __half_as_ushort(__float2half_rn(hv.z));
        hq.w = __half_as_ushort(__float2half_rn(hv.w));
        *reinterpret_cast<ushort4*>(&hh[node * IN_DIM + li * 4]) = hq;

        float pd = hv.x * wd.x + hv.y * wd.y + hv.z * wd.z + hv.w * wd.w;
        float ps = hv.x * ws.x + hv.y * ws.y + hv.z * ws.z + hv.w * ws.w;
        #pragma unroll
        for (int off = 8; off > 0; off >>= 1) {   // reduce within 16-lane group
            pd += __shfl_xor(pd, off, 64);
            ps += __shfl_xor(ps, off, 64);
        }
        if (li == 0) {
            float dv = d[node];
            pairD[node] = make_float2(pd + gate_b[0], dv);
            pairS[node] = make_float2(ps, dv);
        }
    } else {
        int bk  = blockIdx.x - scoreBlocks;       // 0..NBLK-1
        int tid = threadIdx.x;
        for (int b = tid; b < NB; b += blockDim.x) cnt[b] = 0;
        __syncthreads();
        int slice = edge_slice(n_edges);
        int e0 = bk * slice;
        int e1 = min(e0 + slice, n_edges);
        for (int e = e0 + tid * 4; e < e1; e += blockDim.x * 4) {
            if (e + 3 < e1) {
                int4 t4 = *reinterpret_cast<const int4*>(&dst[e]);
                atomicAdd(&cnt[t4.x >> BSH], 1);
                atomicAdd(&cnt[t4.y >> BSH], 1);
                atomicAdd(&cnt[t4.z >> BSH], 1);
                atomicAdd(&cnt[t4.w >> BSH], 1);
            } else {
                for (int k = e; k < e1; ++k) atomicAdd(&cnt[dst[k] >> BSH], 1);
            }
        }
        __syncthreads();
        for (int b = tid; b < NB; b += blockDim.x)
            counts[bk * NB + b] = cnt[b];         // coalesced
    }
}

// ---- K2: per-bucket exclusive scan over the NBLK block counts (4 waves) ----
__global__ void bucket_block_scan_kernel(const int* __restrict__ counts, // [NBLK][NB]
                                         int* __restrict__ within,      // [NB][NBLK]
                                         int* __restrict__ btot,        // [NB]
                                         int NB) {
    __shared__ int wsum[4];
    int b   = blockIdx.x;
    int tid = threadIdx.x;                        // NBLK = 256 threads, 4 waves
    int lane = tid & 63, w = tid >> 6;
    int v = counts[tid * NB + b];                 // strided read, L2-hot
    int incl = v;
    #pragma unroll
    for (int dd = 1; dd < 64; dd <<= 1) {
        int t = __shfl_up(incl, dd, 64);
        if (lane >= dd) incl += t;
    }
    if (lane == 63) wsum[w] = incl;
    __syncthreads();
    int wpre = 0;
    #pragma unroll
    for (int j = 0; j < 4; ++j) if (j < w) wpre += wsum[j];
    incl += wpre;
    within[b * NBLK + tid] = incl - v;            // exclusive, coalesced write
    if (tid == NBLK - 1) btot[b] = incl;
}

// ---- K3: redundant btot scan (3KB, L2-hot) + place into contiguous runs ----
__global__ void bin_place_kernel(const int* __restrict__ src,
                                 const int* __restrict__ dst,
                                 const int* __restrict__ btot,      // [NB]
                                 const int* __restrict__ within,    // [NB][NBLK]
                                 int* __restrict__ bucketBase,      // [NB+1] out (bk 0)
                                 int* __restrict__ entries,
                                 int n_edges, int NB) {
    extern __shared__ int smem[];
    int* base = smem;          // NB: bucketBase[b] + within[b][bk]
    int* cur  = smem + NB;     // NB: btot during scan, then cursor
    __shared__ int wq[4], wp[4];

    int bk  = blockIdx.x;
    int tid = threadIdx.x;                        // 256
    int lane = tid & 63, w = tid >> 6;

    int q  = (NB + 255) >> 8;
    int b0 = min(tid * q, NB);
    int b1 = min(b0 + q, NB);

    int csum = 0;
    for (int b = b0; b < b1; ++b) {
        int v = btot[b];
        cur[b] = v;
        csum += v;
    }
    int s = csum;
    #pragma unroll
    for (int dd = 1; dd < 64; dd <<= 1) {
        int t = __shfl_up(s, dd, 64);
        if (lane >= dd) s += t;
    }
    if (lane == 63) wq[w] = s;
    __syncthreads();
    if (tid == 0) {
        int run = 0;
        for (int j = 0; j < 4; ++j) { wp[j] = run; run += wq[j]; }
    }
    __syncthreads();
    int run = s - csum + wp[w];
    for (int b = b0; b < b1; ++b) {
        int bb = run;                             // bucketBase[b]
        run += cur[b];
        base[b] = bb + within[b * NBLK + bk];
        if (bk == 0) bucketBase[b] = bb;
    }
    if (bk == 0 && tid == 0) bucketBase[NB] = n_edges;
    __syncthreads();
    for (int b = tid; b < NB; b += 256) cur[b] = 0;
    __syncthreads();

    // placement, int4 edge reads (e0 16B-aligned since slice % 4 == 0)
    int slice = edge_slice(n_edges);
    int e0 = bk * slice;
    int e1 = min(e0 + slice, n_edges);
    for (int e = e0 + tid * 4; e < e1; e += blockDim.x * 4) {
        if (e + 3 < e1) {
            int4 t4 = *reinterpret_cast<const int4*>(&dst[e]);
            int4 s4 = *reinterpret_cast<const int4*>(&src[e]);
            int b0i = t4.x >> BSH, b1i = t4.y >> BSH,
                b2i = t4.z >> BSH, b3i = t4.w >> BSH;
            int p0 = atomicAdd(&cur[b0i], 1);
            int p1 = atomicAdd(&cur[b1i], 1);
            int p2 = atomicAdd(&cur[b2i], 1);
            int p3 = atomicAdd(&cur[b3i], 1);
            entries[base[b0i] + p0] = ((t4.x & 63) << 17) | s4.x;
            entries[base[b1i] + p1] = ((t4.y & 63) << 17) | s4.y;
            entries[base[b2i] + p2] = ((t4.z & 63) << 17) | s4.z;
            entries[base[b3i] + p3] = ((t4.w & 63) << 17) | s4.w;
        } else {
            for (int k = e; k < e1; ++k) {
                int t = dst[k];
                int b = t >> BSH;
                int sl = atomicAdd(&cur[b], 1);
                entries[base[b] + sl] = ((t & 63) << 17) | src[k];
            }
        }
    }
}

// ---- K4 fused: LDS sort + gather + z write, 512 thr, ~38KB LDS (4/CU) ------
// Pass1: read entries (global), histogram + coefficient into craw.
// Pass2: re-read entries (L2-hot) and scatter into epk using craw.
__global__ __launch_bounds__(SGT)
void sort_gather_kernel(const unsigned short* __restrict__ hh,
                        const int* __restrict__ entries,
                        const int* __restrict__ bucketBase,
                        const float2* __restrict__ pairD,
                        const float2* __restrict__ pairS,
                        float* __restrict__ z,
                        int n_nodes, int NB) {
    __shared__ int   cnt[64];        // histogram, then cursor
    __shared__ int   nodeBeg[65];    // within-bucket CSR starts
    __shared__ float sDl[64];
    __shared__ float dDl[64];
    __shared__ float craw[CAP];      // per-edge coefficient
    __shared__ int2  epk[CAP];       // sorted (src, c)

    int b   = blockIdx.x;
    int tid = threadIdx.x;           // 512 = 8 waves
    int beg = bucketBase[b];
    int end = bucketBase[b + 1];
    int m   = end - beg;

    if (tid < 64) {
        cnt[tid] = 0;
        int node = (b << BSH) + tid;
        float2 pd = (node < n_nodes) ? pairD[node] : make_float2(0.f, 0.f);
        sDl[tid] = pd.x;
        dDl[tid] = pd.y;
    }
    __syncthreads();

    int w    = tid >> 6;             // 0..7
    int lane = tid & 63;
    int slot = lane >> 3;            // 0..7 edge slot
    int oct  = lane & 7;             // features [oct*8, oct*8+8)
    const int2 zero2 = make_int2(0, 0);

    if (m <= CAP) {
        // pass1: histogram + coefficient
        for (int j = beg + tid; j < end; j += SGT) {
            int e  = entries[j];
            int dl = e >> 17;
            int s  = e & 0x1FFFF;
            float2 ps = pairS[s];                 // random 8B, TLP-hidden
            craw[j - beg] = fast_tanh(sDl[dl] + ps.x) * ps.y * dDl[dl];
            atomicAdd(&cnt[dl], 1);
        }
        __syncthreads();
        // scan 64 bins (wave 0) -> nodeBeg, reset cnt to cursor
        if (tid < 64) {
            int v = cnt[tid];
            int incl = v;
            #pragma unroll
            for (int dd = 1; dd < 64; dd <<= 1) {
                int t = __shfl_up(incl, dd, 64);
                if (tid >= dd) incl += t;
            }
            int excl = incl - v;
            nodeBeg[tid] = excl;
            cnt[tid] = excl;
            if (tid == 0) nodeBeg[64] = m;
        }
        __syncthreads();
        // pass2: re-read entries (L2-hot) and scatter into epk
        for (int j = beg + tid; j < end; j += SGT) {
            int e  = entries[j];
            int dl = e >> 17;
            int pos = atomicAdd(&cnt[dl], 1);
            epk[pos] = make_int2(e & 0x1FFFF, __float_as_int(craw[j - beg]));
        }
        __syncthreads();

        // gather: each wave handles 8 nodes (r = w, w+8, ..., w+56)
        for (int r = w; r < 64; r += 8) {
            int node = (b << BSH) + r;
            if (node >= n_nodes) break;
            int nb = nodeBeg[r];
            int ne = nodeBeg[r + 1];

            float a0[8], a1[8];
            #pragma unroll
            for (int k = 0; k < 8; ++k) { a0[k] = 0.f; a1[k] = 0.f; }

            for (int base2 = nb; base2 < ne; base2 += 16) {
                int j0 = base2 + slot;
                int j1 = base2 + 8 + slot;
                int2 e0 = (j0 < ne) ? epk[j0] : zero2;   // c = 0 when invalid
                int2 e1 = (j1 < ne) ? epk[j1] : zero2;
                const uint4 q0 = *reinterpret_cast<const uint4*>(
                    &hh[(size_t)e0.x * IN_DIM + oct * 8]);
                const uint4 q1 = *reinterpret_cast<const uint4*>(
                    &hh[(size_t)e1.x * IN_DIM + oct * 8]);
                float c0 = __int_as_float(e0.y);
                float c1 = __int_as_float(e1.y);
                float2 f;
                f = half2_to_float2(q0.x); a0[0] = fmaf(f.x, c0, a0[0]); a0[1] = fmaf(f.y, c0, a0[1]);
                f = half2_to_float2(q0.y); a0[2] = fmaf(f.x, c0, a0[2]); a0[3] = fmaf(f.y, c0, a0[3]);
                f = half2_to_float2(q0.z); a0[4] = fmaf(f.x, c0, a0[4]); a0[5] = fmaf(f.y, c0, a0[5]);
                f = half2_to_float2(q0.w); a0[6] = fmaf(f.x, c0, a0[6]); a0[7] = fmaf(f.y, c0, a0[7]);
                f = half2_to_float2(q1.x); a1[0] = fmaf(f.x, c1, a1[0]); a1[1] = fmaf(f.y, c1, a1[1]);
                f = half2_to_float2(q1.y); a1[2] = fmaf(f.x, c1, a1[2]); a1[3] = fmaf(f.y, c1, a1[3]);
                f = half2_to_float2(q1.z); a1[4] = fmaf(f.x, c1, a1[4]); a1[5] = fmaf(f.y, c1, a1[5]);
                f = half2_to_float2(q1.w); a1[6] = fmaf(f.x, c1, a1[6]); a1[7] = fmaf(f.y, c1, a1[7]);
            }

            float a[8];
            #pragma unroll
            for (int k = 0; k < 8; ++k) a[k] = a0[k] + a1[k];
            #pragma unroll
            for (int mm = 8; mm < 64; mm <<= 1) {
                #pragma unroll
                for (int k = 0; k < 8; ++k) a[k] += __shfl_xor(a[k], mm, 64);
            }
            if (slot == 0) {
                float4 lo = make_float4(a[0], a[1], a[2], a[3]);
                float4 hi = make_float4(a[4], a[5], a[6], a[7]);
                *reinterpret_cast<float4*>(&z[(size_t)node * IN_DIM + oct * 8])     = lo;
                *reinterpret_cast<float4*>(&z[(size_t)node * IN_DIM + oct * 8 + 4]) = hi;
            }
        }
    } else {
        // pathological bucket (> CAP edges): quadratic per-node scan.
        for (int r = w; r < 64; r += 8) {
            int node = (b << BSH) + r;
            if (node >= n_nodes) break;
            float a[8];
            #pragma unroll
            for (int k = 0; k < 8; ++k) a[k] = 0.f;
            for (int j = beg + slot; j < end; j += 8) {
                int e = entries[j];
                if ((e >> 17) != r) continue;
                int s = e & 0x1FFFF;
                float2 ps = pairS[s];
                float c = fast_tanh(sDl[r] + ps.x) * ps.y * dDl[r];
                const uint4 q = *reinterpret_cast<const uint4*>(
                    &hh[(size_t)s * IN_DIM + oct * 8]);
                float2 f;
                f = half2_to_float2(q.x); a[0] = fmaf(f.x, c, a[0]); a[1] = fmaf(f.y, c, a[1]);
                f = half2_to_float2(q.y); a[2] = fmaf(f.x, c, a[2]); a[3] = fmaf(f.y, c, a[3]);
                f = half2_to_float2(q.z); a[4] = fmaf(f.x, c, a[4]); a[5] = fmaf(f.y, c, a[5]);
                f = half2_to_float2(q.w); a[6] = fmaf(f.x, c, a[6]); a[7] = fmaf(f.y, c, a[7]);
            }
            #pragma unroll
            for (int mm = 8; mm < 64; mm <<= 1) {
                #pragma unroll
                for (int k = 0; k < 8; ++k) a[k] += __shfl_xor(a[k], mm, 64);
            }
            if (slot == 0) {
                float4 lo = make_float4(a[0], a[1], a[2], a[3]);
                float4 hi = make_float4(a[4], a[5], a[6], a[7]);
                *reinterpret_cast<float4*>(&z[(size_t)node * IN_DIM + oct * 8])     = lo;
                *reinterpret_cast<float4*>(&z[(size_t)node * IN_DIM + oct * 8 + 4]) = hi;
            }
        }
    }
}

// ---- fallback (atomic push) ------------------------------------------------
__global__ void node_scores_kernel(const float* __restrict__ h,
                                   const float* __restrict__ d,
                                   const float* __restrict__ gate_w,
                                   const float* __restrict__ gate_b,
                                   float2* __restrict__ pairD,
                                   float2* __restrict__ pairS,
                                   int n_nodes) {
    int gid  = blockIdx.x * blockDim.x + threadIdx.x;
    int node = gid >> 6;
    int lane = threadIdx.x & 63;
    if (node >= n_nodes) return;
    float hv = h[node * IN_DIM + lane];
    float pd = hv * gate_w[lane];
    float ps = hv * gate_w[IN_DIM + lane];
    #pragma unroll
    for (int off = 32; off > 0; off >>= 1) {
        pd += __shfl_xor(pd, off, 64);
        ps += __shfl_xor(ps, off, 64);
    }
    if (lane == 0) {
        float dv = d[node];
        pairD[node] = make_float2(pd + gate_b[0], dv);
        pairS[node] = make_float2(ps, dv);
    }
}

__global__ void edge_scatter_atomic_kernel(const float* __restrict__ h,
                                           const int* __restrict__ src,
                                           const int* __restrict__ dst,
                                           const float2* __restrict__ pairD,
                                           const float2* __restrict__ pairS,
                                           float* __restrict__ z,
                                           int n_edges) {
    int gid  = blockIdx.x * blockDim.x + threadIdx.x;
    int e    = gid >> 6;
    int lane = threadIdx.x & 63;
    if (e >= n_edges) return;
    int s = src[e];
    int t = dst[e];
    float2 pt = pairD[t];
    float2 ps = pairS[s];
    float c = tanhf(pt.x + ps.x) * pt.y * ps.y;
    atomicAdd(&z[t * IN_DIM + lane], h[s * IN_DIM + lane] * c);
}

extern "C" void kernel_launch(void* const* d_in, const int* in_sizes, int n_in,
                              void* d_out, int out_size, void* d_ws, size_t ws_size,
                              hipStream_t stream) {
    const float* h      = (const float*)d_in[0];
    const float* d      = (const float*)d_in[1];
    const int*   src    = (const int*)d_in[2];
    const int*   dst    = (const int*)d_in[3];
    const float* gate_w = (const float*)d_in[4];
    const float* gate_b = (const float*)d_in[5];

    const int n_nodes = in_sizes[1];
    const int n_edges = in_sizes[2];
    float* z = (float*)d_out;

    const int NB = (n_nodes + 63) >> BSH;   // 64-node buckets (782)

    // ws layout: pairD, pairS, hh (fp16 h), entries, counts, within, btot,
    //            bucketBase
    size_t need = (size_t)n_nodes * 2 * sizeof(float2)
                + (size_t)n_nodes * IN_DIM * sizeof(unsigned short)
                + (size_t)n_edges * sizeof(int)
                + (size_t)(2 * NB * NBLK + 2 * NB + 1) * sizeof(int);

    if (ws_size < need || NB > 1024 || n_nodes > (1 << 17)) {
        float2* pairD = (float2*)d_ws;
        float2* pairS = pairD + n_nodes;
        hipMemsetAsync(z, 0, (size_t)out_size * sizeof(float), stream);
        {
            int total = n_nodes * 64, threads = 256;
            node_scores_kernel<<<(total + threads - 1) / threads, threads, 0, stream>>>(
                h, d, gate_w, gate_b, pairD, pairS, n_nodes);
        }
        {
            long long total = (long long)n_edges * 64;
            int threads = 256;
            edge_scatter_atomic_kernel<<<(int)((total + threads - 1) / threads), threads, 0, stream>>>(
                h, src, dst, pairD, pairS, z, n_edges);
        }
        return;
    }

    float2*         pairD      = (float2*)d_ws;
    float2*         pairS      = pairD + n_nodes;
    unsigned short* hh         = (unsigned short*)(pairS + n_nodes);
    int*            entries    = (int*)(hh + (size_t)n_nodes * IN_DIM);
    int*            counts     = entries + n_edges;         // [NBLK][NB]
    int*            within     = counts + NBLK * NB;        // [NB][NBLK]
    int*            btot       = within + NB * NBLK;        // NB
    int*            bucketBase = btot + NB;                 // NB+1

    const int scoreBlocks = (n_nodes * 16 + 255) / 256;     // 4 nodes per wave

    // K1: node scores (float4) + h->fp16 + per-block bucket histogram
    scores_and_count_kernel<<<scoreBlocks + NBLK, 256, NB * sizeof(int), stream>>>(
        h, d, gate_w, gate_b, pairD, pairS, hh, dst, counts,
        n_nodes, n_edges, NB, scoreBlocks);

    // K2: per-bucket scan across blocks -> within, btot
    bucket_block_scan_kernel<<<NB, NBLK, 0, stream>>>(counts, within, btot, NB);

    // K3: redundant btot scan + place (block 0 publishes bucketBase)
    bin_place_kernel<<<NBLK, 256, 2 * NB * sizeof(int), stream>>>(
        src, dst, btot, within, bucketBase, entries, n_edges, NB);

    // K4: fused LDS sort + gather + z write (512 threads, 4 blocks/CU)
    sort_gather_kernel<<<NB, SGT, 0, stream>>>(
        hh, entries, bucketBase, pairD, pairS, z, n_nodes, NB);
}

// Round 18
// 57.081 us; speedup vs baseline: 1.2507x; 1.0031x over previous
//
#include <hip/hip_runtime.h>
#include <hip/hip_fp16.h>
#include <cmath>

#define IN_DIM 64
#define NBLK   256     // blocks for bin-count / bin-place (== K2 scan width)
#define BSH    6       // 64 nodes per bucket
#define CAP    3072    // max edges per bucket held in LDS
#define SGT    512     // sort_gather threads (38KB LDS -> 4 blocks/CU)
#define EPT    (CAP / SGT)   // max entries per thread in K4 (= 6)

// slice of edges per count/place block — identical in K1 and K3, multiple of 4
__host__ __device__ __forceinline__ int edge_slice(int n_edges) {
    return (((n_edges + NBLK - 1) / NBLK) + 3) & ~3;
}

// fast tanh: 1 - 2/(e^{2x}+1); saturates correctly (+inf->1, -inf->-1)
__device__ __forceinline__ float fast_tanh(float x) {
    return 1.0f - __fdividef(2.0f, __expf(2.0f * x) + 1.0f);
}

__device__ __forceinline__ float2 half2_to_float2(unsigned int u) {
    __half2 h = *reinterpret_cast<__half2*>(&u);
    return __half22float2(h);
}

// ---- K1 fused: node scores (4 nodes/wave, float4) + h->fp16 + bucket count -
__global__ void scores_and_count_kernel(const float* __restrict__ h,
                                        const float* __restrict__ d,
                                        const float* __restrict__ gate_w,
                                        const float* __restrict__ gate_b,
                                        float2* __restrict__ pairD,
                                        float2* __restrict__ pairS,
                                        unsigned short* __restrict__ hh,  // fp16 h
                                        const int* __restrict__ dst,
                                        int* __restrict__ counts,   // [NBLK][NB]
                                        int n_nodes, int n_edges, int NB,
                                        int scoreBlocks) {
    extern __shared__ int cnt[];                  // NB ints (count role only)
    if ((int)blockIdx.x < scoreBlocks) {
        int gid  = blockIdx.x * blockDim.x + threadIdx.x;
        int node = gid >> 4;                      // 16 lanes per node
        int li   = threadIdx.x & 15;              // feature quad index
        if (node >= n_nodes) return;

        const float4 hv = *reinterpret_cast<const float4*>(&h[node * IN_DIM + li * 4]);
        const float4 wd = *reinterpret_cast<const float4*>(&gate_w[li * 4]);
        const float4 ws = *reinterpret_cast<const float4*>(&gate_w[IN_DIM + li * 4]);

        ushort4 hq;
        hq.x = __half_as_ushort(__float2half_rn(hv.x));
        hq.y = __half_as_ushort(__float2half_rn(hv.y));
        hq.z = __half_as_ushort(__float2half_rn(hv.z));
        hq.w = __half_as_ushort(__float2half_rn(hv.w));
        *reinterpret_cast<ushort4*>(&hh[node * IN_DIM + li * 4]) = hq;

        float pd = hv.x * wd.x + hv.y * wd.y + hv.z * wd.z + hv.w * wd.w;
        float ps = hv.x * ws.x + hv.y * ws.y + hv.z * ws.z + hv.w * ws.w;
        #pragma unroll
        for (int off = 8; off > 0; off >>= 1) {   // reduce within 16-lane group
            pd += __shfl_xor(pd, off, 64);
            ps += __shfl_xor(ps, off, 64);
        }
        if (li == 0) {
            float dv = d[node];
            pairD[node] = make_float2(pd + gate_b[0], dv);
            pairS[node] = make_float2(ps, dv);
        }
    } else {
        int bk  = blockIdx.x - scoreBlocks;       // 0..NBLK-1
        int tid = threadIdx.x;
        for (int b = tid; b < NB; b += blockDim.x) cnt[b] = 0;
        __syncthreads();
        int slice = edge_slice(n_edges);
        int e0 = bk * slice;
        int e1 = min(e0 + slice, n_edges);
        for (int e = e0 + tid * 4; e < e1; e += blockDim.x * 4) {
            if (e + 3 < e1) {
                int4 t4 = *reinterpret_cast<const int4*>(&dst[e]);
                atomicAdd(&cnt[t4.x >> BSH], 1);
                atomicAdd(&cnt[t4.y >> BSH], 1);
                atomicAdd(&cnt[t4.z >> BSH], 1);
                atomicAdd(&cnt[t4.w >> BSH], 1);
            } else {
                for (int k = e; k < e1; ++k) atomicAdd(&cnt[dst[k] >> BSH], 1);
            }
        }
        __syncthreads();
        for (int b = tid; b < NB; b += blockDim.x)
            counts[bk * NB + b] = cnt[b];         // coalesced
    }
}

// ---- K2: per-bucket exclusive scan over the NBLK block counts (4 waves) ----
__global__ void bucket_block_scan_kernel(const int* __restrict__ counts, // [NBLK][NB]
                                         int* __restrict__ within,      // [NB][NBLK]
                                         int* __restrict__ btot,        // [NB]
                                         int NB) {
    __shared__ int wsum[4];
    int b   = blockIdx.x;
    int tid = threadIdx.x;                        // NBLK = 256 threads, 4 waves
    int lane = tid & 63, w = tid >> 6;
    int v = counts[tid * NB + b];                 // strided read, L2-hot
    int incl = v;
    #pragma unroll
    for (int dd = 1; dd < 64; dd <<= 1) {
        int t = __shfl_up(incl, dd, 64);
        if (lane >= dd) incl += t;
    }
    if (lane == 63) wsum[w] = incl;
    __syncthreads();
    int wpre = 0;
    #pragma unroll
    for (int j = 0; j < 4; ++j) if (j < w) wpre += wsum[j];
    incl += wpre;
    within[b * NBLK + tid] = incl - v;            // exclusive, coalesced write
    if (tid == NBLK - 1) btot[b] = incl;
}

// ---- K3: redundant btot scan (3KB, L2-hot) + place into contiguous runs ----
__global__ void bin_place_kernel(const int* __restrict__ src,
                                 const int* __restrict__ dst,
                                 const int* __restrict__ btot,      // [NB]
                                 const int* __restrict__ within,    // [NB][NBLK]
                                 int* __restrict__ bucketBase,      // [NB+1] out (bk 0)
                                 int* __restrict__ entries,
                                 int n_edges, int NB) {
    extern __shared__ int smem[];
    int* base = smem;          // NB: bucketBase[b] + within[b][bk]
    int* cur  = smem + NB;     // NB: btot during scan, then cursor
    __shared__ int wq[4], wp[4];

    int bk  = blockIdx.x;
    int tid = threadIdx.x;                        // 256
    int lane = tid & 63, w = tid >> 6;

    int q  = (NB + 255) >> 8;
    int b0 = min(tid * q, NB);
    int b1 = min(b0 + q, NB);

    int csum = 0;
    for (int b = b0; b < b1; ++b) {
        int v = btot[b];
        cur[b] = v;
        csum += v;
    }
    int s = csum;
    #pragma unroll
    for (int dd = 1; dd < 64; dd <<= 1) {
        int t = __shfl_up(s, dd, 64);
        if (lane >= dd) s += t;
    }
    if (lane == 63) wq[w] = s;
    __syncthreads();
    if (tid == 0) {
        int run = 0;
        for (int j = 0; j < 4; ++j) { wp[j] = run; run += wq[j]; }
    }
    __syncthreads();
    int run = s - csum + wp[w];
    for (int b = b0; b < b1; ++b) {
        int bb = run;                             // bucketBase[b]
        run += cur[b];
        base[b] = bb + within[b * NBLK + bk];
        if (bk == 0) bucketBase[b] = bb;
    }
    if (bk == 0 && tid == 0) bucketBase[NB] = n_edges;
    __syncthreads();
    for (int b = tid; b < NB; b += 256) cur[b] = 0;
    __syncthreads();

    // placement, int4 edge reads (e0 16B-aligned since slice % 4 == 0)
    int slice = edge_slice(n_edges);
    int e0 = bk * slice;
    int e1 = min(e0 + slice, n_edges);
    for (int e = e0 + tid * 4; e < e1; e += blockDim.x * 4) {
        if (e + 3 < e1) {
            int4 t4 = *reinterpret_cast<const int4*>(&dst[e]);
            int4 s4 = *reinterpret_cast<const int4*>(&src[e]);
            int b0i = t4.x >> BSH, b1i = t4.y >> BSH,
                b2i = t4.z >> BSH, b3i = t4.w >> BSH;
            int p0 = atomicAdd(&cur[b0i], 1);
            int p1 = atomicAdd(&cur[b1i], 1);
            int p2 = atomicAdd(&cur[b2i], 1);
            int p3 = atomicAdd(&cur[b3i], 1);
            entries[base[b0i] + p0] = ((t4.x & 63) << 17) | s4.x;
            entries[base[b1i] + p1] = ((t4.y & 63) << 17) | s4.y;
            entries[base[b2i] + p2] = ((t4.z & 63) << 17) | s4.z;
            entries[base[b3i] + p3] = ((t4.w & 63) << 17) | s4.w;
        } else {
            for (int k = e; k < e1; ++k) {
                int t = dst[k];
                int b = t >> BSH;
                int sl = atomicAdd(&cur[b], 1);
                entries[base[b] + sl] = ((t & 63) << 17) | src[k];
            }
        }
    }
}

// ---- K4 fused: LDS sort + gather + z write, 512 thr, ~38KB LDS (4/CU) ------
// Pass1: read entries ONCE into registers (<=6/thread), histogram + coeff.
// Pass2: register -> LDS scatter (no global traffic).
__global__ __launch_bounds__(SGT)
void sort_gather_kernel(const unsigned short* __restrict__ hh,
                        const int* __restrict__ entries,
                        const int* __restrict__ bucketBase,
                        const float2* __restrict__ pairD,
                        const float2* __restrict__ pairS,
                        float* __restrict__ z,
                        int n_nodes, int NB) {
    __shared__ int   cnt[64];        // histogram, then cursor
    __shared__ int   nodeBeg[65];    // within-bucket CSR starts
    __shared__ float sDl[64];
    __shared__ float dDl[64];
    __shared__ float craw[CAP];      // per-edge coefficient (pass1 output)
    __shared__ int2  epk[CAP];       // sorted (src, c)

    int b   = blockIdx.x;
    int tid = threadIdx.x;           // 512 = 8 waves
    int beg = bucketBase[b];
    int end = bucketBase[b + 1];
    int m   = end - beg;

    if (tid < 64) {
        cnt[tid] = 0;
        int node = (b << BSH) + tid;
        float2 pd = (node < n_nodes) ? pairD[node] : make_float2(0.f, 0.f);
        sDl[tid] = pd.x;
        dDl[tid] = pd.y;
    }
    __syncthreads();

    int w    = tid >> 6;             // 0..7
    int lane = tid & 63;
    int slot = lane >> 3;            // 0..7 edge slot
    int oct  = lane & 7;             // features [oct*8, oct*8+8)
    const int2 zero2 = make_int2(0, 0);

    if (m <= CAP) {
        // pass1: read entries once -> registers; histogram + coefficient
        int re[EPT];
        #pragma unroll
        for (int k = 0; k < EPT; ++k) {
            int j = beg + tid + k * SGT;
            re[k] = -1;
            if (j < end) {
                int e  = entries[j];
                re[k] = e;
                int dl = e >> 17;
                int s  = e & 0x1FFFF;
                float2 ps = pairS[s];             // random 8B, TLP-hidden
                craw[j - beg] = fast_tanh(sDl[dl] + ps.x) * ps.y * dDl[dl];
                atomicAdd(&cnt[dl], 1);
            }
        }
        __syncthreads();
        // scan 64 bins (wave 0) -> nodeBeg, reset cnt to cursor
        if (tid < 64) {
            int v = cnt[tid];
            int incl = v;
            #pragma unroll
            for (int dd = 1; dd < 64; dd <<= 1) {
                int t = __shfl_up(incl, dd, 64);
                if (tid >= dd) incl += t;
            }
            int excl = incl - v;
            nodeBeg[tid] = excl;
            cnt[tid] = excl;
            if (tid == 0) nodeBeg[64] = m;
        }
        __syncthreads();
        // pass2: register -> LDS scatter (no global reads)
        #pragma unroll
        for (int k = 0; k < EPT; ++k) {
            int e = re[k];
            if (e >= 0) {
                int j  = beg + tid + k * SGT;
                int dl = e >> 17;
                int pos = atomicAdd(&cnt[dl], 1);
                epk[pos] = make_int2(e & 0x1FFFF, __float_as_int(craw[j - beg]));
            }
        }
        __syncthreads();

        // gather: each wave handles 8 nodes (r = w, w+8, ..., w+56)
        for (int r = w; r < 64; r += 8) {
            int node = (b << BSH) + r;
            if (node >= n_nodes) break;
            int nb = nodeBeg[r];
            int ne = nodeBeg[r + 1];

            float a0[8], a1[8];
            #pragma unroll
            for (int k = 0; k < 8; ++k) { a0[k] = 0.f; a1[k] = 0.f; }

            for (int base2 = nb; base2 < ne; base2 += 16) {
                int j0 = base2 + slot;
                int j1 = base2 + 8 + slot;
                int2 e0 = (j0 < ne) ? epk[j0] : zero2;   // c = 0 when invalid
                int2 e1 = (j1 < ne) ? epk[j1] : zero2;
                const uint4 q0 = *reinterpret_cast<const uint4*>(
                    &hh[(size_t)e0.x * IN_DIM + oct * 8]);
                const uint4 q1 = *reinterpret_cast<const uint4*>(
                    &hh[(size_t)e1.x * IN_DIM + oct * 8]);
                float c0 = __int_as_float(e0.y);
                float c1 = __int_as_float(e1.y);
                float2 f;
                f = half2_to_float2(q0.x); a0[0] = fmaf(f.x, c0, a0[0]); a0[1] = fmaf(f.y, c0, a0[1]);
                f = half2_to_float2(q0.y); a0[2] = fmaf(f.x, c0, a0[2]); a0[3] = fmaf(f.y, c0, a0[3]);
                f = half2_to_float2(q0.z); a0[4] = fmaf(f.x, c0, a0[4]); a0[5] = fmaf(f.y, c0, a0[5]);
                f = half2_to_float2(q0.w); a0[6] = fmaf(f.x, c0, a0[6]); a0[7] = fmaf(f.y, c0, a0[7]);
                f = half2_to_float2(q1.x); a1[0] = fmaf(f.x, c1, a1[0]); a1[1] = fmaf(f.y, c1, a1[1]);
                f = half2_to_float2(q1.y); a1[2] = fmaf(f.x, c1, a1[2]); a1[3] = fmaf(f.y, c1, a1[3]);
                f = half2_to_float2(q1.z); a1[4] = fmaf(f.x, c1, a1[4]); a1[5] = fmaf(f.y, c1, a1[5]);
                f = half2_to_float2(q1.w); a1[6] = fmaf(f.x, c1, a1[6]); a1[7] = fmaf(f.y, c1, a1[7]);
            }

            float a[8];
            #pragma unroll
            for (int k = 0; k < 8; ++k) a[k] = a0[k] + a1[k];
            #pragma unroll
            for (int mm = 8; mm < 64; mm <<= 1) {
                #pragma unroll
                for (int k = 0; k < 8; ++k) a[k] += __shfl_xor(a[k], mm, 64);
            }
            if (slot == 0) {
                float4 lo = make_float4(a[0], a[1], a[2], a[3]);
                float4 hi = make_float4(a[4], a[5], a[6], a[7]);
                *reinterpret_cast<float4*>(&z[(size_t)node * IN_DIM + oct * 8])     = lo;
                *reinterpret_cast<float4*>(&z[(size_t)node * IN_DIM + oct * 8 + 4]) = hi;
            }
        }
    } else {
        // pathological bucket (> CAP edges): quadratic per-node scan.
        for (int r = w; r < 64; r += 8) {
            int node = (b << BSH) + r;
            if (node >= n_nodes) break;
            float a[8];
            #pragma unroll
            for (int k = 0; k < 8; ++k) a[k] = 0.f;
            for (int j = beg + slot; j < end; j += 8) {
                int e = entries[j];
                if ((e >> 17) != r) continue;
                int s = e & 0x1FFFF;
                float2 ps = pairS[s];
                float c = fast_tanh(sDl[r] + ps.x) * ps.y * dDl[r];
                const uint4 q = *reinterpret_cast<const uint4*>(
                    &hh[(size_t)s * IN_DIM + oct * 8]);
                float2 f;
                f = half2_to_float2(q.x); a[0] = fmaf(f.x, c, a[0]); a[1] = fmaf(f.y, c, a[1]);
                f = half2_to_float2(q.y); a[2] = fmaf(f.x, c, a[2]); a[3] = fmaf(f.y, c, a[3]);
                f = half2_to_float2(q.z); a[4] = fmaf(f.x, c, a[4]); a[5] = fmaf(f.y, c, a[5]);
                f = half2_to_float2(q.w); a[6] = fmaf(f.x, c, a[6]); a[7] = fmaf(f.y, c, a[7]);
            }
            #pragma unroll
            for (int mm = 8; mm < 64; mm <<= 1) {
                #pragma unroll
                for (int k = 0; k < 8; ++k) a[k] += __shfl_xor(a[k], mm, 64);
            }
            if (slot == 0) {
                float4 lo = make_float4(a[0], a[1], a[2], a[3]);
                float4 hi = make_float4(a[4], a[5], a[6], a[7]);
                *reinterpret_cast<float4*>(&z[(size_t)node * IN_DIM + oct * 8])     = lo;
                *reinterpret_cast<float4*>(&z[(size_t)node * IN_DIM + oct * 8 + 4]) = hi;
            }
        }
    }
}

// ---- fallback (atomic push) ------------------------------------------------
__global__ void node_scores_kernel(const float* __restrict__ h,
                                   const float* __restrict__ d,
                                   const float* __restrict__ gate_w,
                                   const float* __restrict__ gate_b,
                                   float2* __restrict__ pairD,
                                   float2* __restrict__ pairS,
                                   int n_nodes) {
    int gid  = blockIdx.x * blockDim.x + threadIdx.x;
    int node = gid >> 6;
    int lane = threadIdx.x & 63;
    if (node >= n_nodes) return;
    float hv = h[node * IN_DIM + lane];
    float pd = hv * gate_w[lane];
    float ps = hv * gate_w[IN_DIM + lane];
    #pragma unroll
    for (int off = 32; off > 0; off >>= 1) {
        pd += __shfl_xor(pd, off, 64);
        ps += __shfl_xor(ps, off, 64);
    }
    if (lane == 0) {
        float dv = d[node];
        pairD[node] = make_float2(pd + gate_b[0], dv);
        pairS[node] = make_float2(ps, dv);
    }
}

__global__ void edge_scatter_atomic_kernel(const float* __restrict__ h,
                                           const int* __restrict__ src,
                                           const int* __restrict__ dst,
                                           const float2* __restrict__ pairD,
                                           const float2* __restrict__ pairS,
                                           float* __restrict__ z,
                                           int n_edges) {
    int gid  = blockIdx.x * blockDim.x + threadIdx.x;
    int e    = gid >> 6;
    int lane = threadIdx.x & 63;
    if (e >= n_edges) return;
    int s = src[e];
    int t = dst[e];
    float2 pt = pairD[t];
    float2 ps = pairS[s];
    float c = tanhf(pt.x + ps.x) * pt.y * ps.y;
    atomicAdd(&z[t * IN_DIM + lane], h[s * IN_DIM + lane] * c);
}

extern "C" void kernel_launch(void* const* d_in, const int* in_sizes, int n_in,
                              void* d_out, int out_size, void* d_ws, size_t ws_size,
                              hipStream_t stream) {
    const float* h      = (const float*)d_in[0];
    const float* d      = (const float*)d_in[1];
    const int*   src    = (const int*)d_in[2];
    const int*   dst    = (const int*)d_in[3];
    const float* gate_w = (const float*)d_in[4];
    const float* gate_b = (const float*)d_in[5];

    const int n_nodes = in_sizes[1];
    const int n_edges = in_sizes[2];
    float* z = (float*)d_out;

    const int NB = (n_nodes + 63) >> BSH;   // 64-node buckets (782)

    // ws layout: pairD, pairS, hh (fp16 h), entries, counts, within, btot,
    //            bucketBase
    size_t need = (size_t)n_nodes * 2 * sizeof(float2)
                + (size_t)n_nodes * IN_DIM * sizeof(unsigned short)
                + (size_t)n_edges * sizeof(int)
                + (size_t)(2 * NB * NBLK + 2 * NB + 1) * sizeof(int);

    if (ws_size < need || NB > 1024 || n_nodes > (1 << 17)) {
        float2* pairD = (float2*)d_ws;
        float2* pairS = pairD + n_nodes;
        hipMemsetAsync(z, 0, (size_t)out_size * sizeof(float), stream);
        {
            int total = n_nodes * 64, threads = 256;
            node_scores_kernel<<<(total + threads - 1) / threads, threads, 0, stream>>>(
                h, d, gate_w, gate_b, pairD, pairS, n_nodes);
        }
        {
            long long total = (long long)n_edges * 64;
            int threads = 256;
            edge_scatter_atomic_kernel<<<(int)((total + threads - 1) / threads), threads, 0, stream>>>(
                h, src, dst, pairD, pairS, z, n_edges);
        }
        return;
    }

    float2*         pairD      = (float2*)d_ws;
    float2*         pairS      = pairD + n_nodes;
    unsigned short* hh         = (unsigned short*)(pairS + n_nodes);
    int*            entries    = (int*)(hh + (size_t)n_nodes * IN_DIM);
    int*            counts     = entries + n_edges;         // [NBLK][NB]
    int*            within     = counts + NBLK * NB;        // [NB][NBLK]
    int*            btot       = within + NB * NBLK;        // NB
    int*            bucketBase = btot + NB;                 // NB+1

    const int scoreBlocks = (n_nodes * 16 + 255) / 256;     // 4 nodes per wave

    // K1: node scores (float4) + h->fp16 + per-block bucket histogram
    scores_and_count_kernel<<<scoreBlocks + NBLK, 256, NB * sizeof(int), stream>>>(
        h, d, gate_w, gate_b, pairD, pairS, hh, dst, counts,
        n_nodes, n_edges, NB, scoreBlocks);

    // K2: per-bucket scan across blocks -> within, btot
    bucket_block_scan_kernel<<<NB, NBLK, 0, stream>>>(counts, within, btot, NB);

    // K3: redundant btot scan + place (block 0 publishes bucketBase)
    bin_place_kernel<<<NBLK, 256, 2 * NB * sizeof(int), stream>>>(
        src, dst, btot, within, bucketBase, entries, n_edges, NB);

    // K4: fused LDS sort + gather + z write (512 threads, 4 blocks/CU)
    sort_gather_kernel<<<NB, SGT, 0, stream>>>(
        hh, entries, bucketBase, pairD, pairS, z, n_nodes, NB);
}